// Round 5
// baseline (239.334 us; speedup 1.0000x reference)
//
#include <hip/hip_runtime.h>
#include <math.h>

// Problem constants (from reference setup_inputs)
constexpr int B = 32, D = 64, H = 192, W = 128, K = 64;
constexpr int QBLK = 4;          // i-row chunks per batch -> grid = B*QBLK = 128 blocks
constexpr int ROWS = K / QBLK;   // 16 i-rows per block
constexpr int NTHR = 256;        // 4 waves

__global__ __launch_bounds__(NTHR) void tagloss_kernel(
    const float* __restrict__ ebd,   // [B, D, H, W]
    const float* __restrict__ kpts,  // [B, K, 2]
    const int*   __restrict__ tags,  // [B, K]
    float* __restrict__ out)         // [1]
{
    const int blk  = blockIdx.x;
    const int b    = blk / QBLK;
    const int q    = blk % QBLK;
    const int t    = threadIdx.x;
    const int lane = t & 63;
    const int wave = t >> 6;

    __shared__ float e[D][K];    // 16 KiB: e[d][k] = ebd[b, d, r_k, c_k]
    __shared__ int   stags[K];
    __shared__ int   rr[K], cc[K];

    if (t < K) {
        stags[t] = tags[b * K + t];
        float kr = kpts[(b * K + t) * 2 + 0];
        float kc = kpts[(b * K + t) * 2 + 1];
        rr[t] = (int)floorf(kr * (float)H);   // row index into H
        cc[t] = (int)floorf(kc * (float)W);   // col index into W
    }
    __syncthreads();

    // Gather: 4096 elements, 16 per thread. Consecutive t -> consecutive k
    // (same d per 64-lane group); addresses are random per keypoint (inherent).
    const float* eb = ebd + (size_t)b * D * H * W;
    for (int n = t; n < D * K; n += NTHR) {
        int d = n >> 6;      // n / K
        int k = n & 63;      // n % K
        e[d][k] = eb[(size_t)d * (H * W) + rr[k] * W + cc[k]];
    }
    __syncthreads();

    // Each lane caches its j-column in registers (stride-1 LDS read: 2-way, free).
    float ej[D];
#pragma unroll
    for (int d = 0; d < D; ++d) ej[d] = e[d][lane];

    const int jtag = stags[lane];

    float acc = 0.0f;
    // Pairs: i = q*ROWS + it*4 + wave (wave-uniform -> LDS broadcast), j = lane.
#pragma unroll
    for (int it = 0; it < ROWS / 4; ++it) {
        const int i = q * ROWS + it * 4 + wave;
        float s = 0.0f;
#pragma unroll
        for (int d = 0; d < D; ++d) {
            float diff = e[d][i] - ej[d];   // broadcast read - conflict-free
            s = fmaf(diff, diff, s);
        }
        float expo = s * (1.0f / (float)D);
        float ps   = 2.0f / (1.0f + expf(expo));
        float ts   = (stags[i] == jtag) ? 1.0f : 0.0f;
        float dd   = ps - ts;
        acc = fmaf(dd, dd, acc);
    }

    // Reduce across the wave (64 lanes), then across the 4 waves.
#pragma unroll
    for (int off = 32; off; off >>= 1) acc += __shfl_down(acc, off, 64);

    __shared__ float wsum[4];
    if (lane == 0) wsum[wave] = acc;
    __syncthreads();
    if (t == 0) {
        float tot = (wsum[0] + wsum[1]) + (wsum[2] + wsum[3]);
        // final = sum over all (b,i,j) of (ps-ts)^2 / (B*K*K)
        atomicAdd(out, tot * (1.0f / ((float)B * (float)K * (float)K)));
    }
}

extern "C" void kernel_launch(void* const* d_in, const int* in_sizes, int n_in,
                              void* d_out, int out_size, void* d_ws, size_t ws_size,
                              hipStream_t stream) {
    const float* ebd  = (const float*)d_in[0];
    const float* kpts = (const float*)d_in[1];
    const int*   tags = (const int*)d_in[2];
    float* out = (float*)d_out;

    // d_out is poisoned to 0xAA before every timed launch -> zero it first.
    hipMemsetAsync(out, 0, sizeof(float), stream);
    tagloss_kernel<<<B * QBLK, NTHR, 0, stream>>>(ebd, kpts, tags, out);
}